// Round 4
// baseline (119.279 us; speedup 1.0000x reference)
//
#include <hip/hip_runtime.h>

#define J 17
#define F 128
#define TB 16          // batches per block (= MFMA N dim)
#define THREADS 512    // 8 waves; wave w owns g band [16w, 16w+16)
#define JSTRIDE 9      // xs j-slots (chunk0 uses 9, chunk1 uses 8 of them)

typedef __attribute__((ext_vector_type(4))) float f32x4;
typedef __attribute__((ext_vector_type(8))) short bf16x8;   // 8 bf16 in 4 VGPRs

// round-to-nearest-even f32 -> bf16
__device__ __forceinline__ unsigned short f2bf(float f) {
    unsigned u = __builtin_bit_cast(unsigned, f);
    u += 0x7fffu + ((u >> 16) & 1u);
    return (unsigned short)(u >> 16);
}
__device__ __forceinline__ float bf2f(unsigned short s) {
    return __builtin_bit_cast(float, (unsigned)s << 16);
}

// whole-vector FMA so LLVM can select v_pk_fma_f32 (2x f32 per instr)
__device__ __forceinline__ f32x4 fma4(float a, f32x4 v, f32x4 c) {
    f32x4 av = {a, a, a, a};
    return __builtin_elementwise_fma(av, v, c);
}

// ws: f32[0..288] = A_off (diag zeroed); f32[289..305] = A_diag;
// byte 2048: WT bf16 [2][g=128][k=128]  (WT[mat][g][k] = bf16(W[mat][k][g]))
__global__ void prep(const float* __restrict__ W, const float* __restrict__ adj,
                     const float* __restrict__ adj2, float* __restrict__ wsA,
                     unsigned short* __restrict__ WT) {
    int t = blockIdx.x * 256 + threadIdx.x;
    for (int idx = t; idx < 2 * F * F; idx += 16 * 256) {
        int mat = idx >> 14;
        int rem = idx & 16383;
        int g = rem >> 7, k = rem & 127;
        WT[idx] = f2bf(W[mat * 16384 + k * F + g]);
    }
    if (blockIdx.x == 0) {
        for (int idx = threadIdx.x; idx < J * J; idx += 256) {
            int i = idx / J, j = idx % J;
            float a = 0.5f * (adj[i*J+j] + adj2[i*J+j] + adj[j*J+i] + adj2[j*J+i]);
            wsA[idx] = (i == j) ? 0.0f : a;
            if (i == j) wsA[J * J + i] = a;
        }
    }
}

// One j-chunk: stage x[:, J0..J0+JC) into xs (bf16, swizzled), then pass A
// (diag, wf0) + pass B (off-diag, wf1) for those j. acc is linear in j, so
// chunk-splitting is exact.
template<int JC, int J0>
__device__ __forceinline__ void chunk(
    const float* __restrict__ x, unsigned char* xs, const float* Ms,
    const float* __restrict__ Aoff, const float* __restrict__ Adiag,
    const unsigned short* __restrict__ WT, f32x4* acc,
    int tid, int b0, int lrow, int lq, int grow, int gq) {

    // ---- stage: JC*512 float4, coalesced (512B runs per (b,jj) row) ----
#pragma unroll
    for (int it = 0; it < JC; ++it) {
        int fi = it * THREADS + tid;
        int b  = fi / (JC * 32);
        int r  = fi - b * (JC * 32);
        int jj = r >> 5;
        int k4 = r & 31;
        const float4 v = *(const float4*)(x + (size_t)(b0 + b) * (J * F)
                                            + (J0 + jj) * F + k4 * 4);
        unsigned byte = (unsigned)(((b * JSTRIDE + jj) << 8) + (k4 << 3));
        byte ^= (unsigned)((b & 7) << 4);
        ushort4 u;
        u.x = f2bf(v.x); u.y = f2bf(v.y); u.z = f2bf(v.z); u.w = f2bf(v.w);
        *(ushort4*)(xs + byte) = u;
    }
    __syncthreads();

    const unsigned rbase = (unsigned)(lrow * (JSTRIDE * 256));
    const unsigned swz   = (unsigned)((lrow & 7) << 4);

    // ---- pass A: diagonal path (wf0 only) ----
    {
        bf16x8 wf[4];
#pragma unroll
        for (int ks = 0; ks < 4; ++ks)
            wf[ks] = __builtin_bit_cast(bf16x8,
                *(const uint4*)(WT + (size_t)grow * F + ks * 32 + lq * 8));
#pragma unroll
        for (int jj = 0; jj < JC; ++jj) {
            constexpr int dummy = 0; (void)dummy;
            f32x4 h0 = {0.f, 0.f, 0.f, 0.f};
#pragma unroll
            for (int ks = 0; ks < 4; ++ks) {
                unsigned byte = (rbase + (unsigned)(jj * 256 + ks * 64 + lq * 16)) ^ swz;
                bf16x8 xf = __builtin_bit_cast(bf16x8, *(const uint4*)(xs + byte));
                h0 = __builtin_amdgcn_mfma_f32_16x16x32_bf16(wf[ks], xf, h0, 0, 0, 0);
            }
            const int j = J0 + jj;
            f32x4 mj = *(const f32x4*)&Ms[j * F + gq];
            acc[j] = fma4(Adiag[j], mj * h0, acc[j]);
        }
    }

    // ---- pass B: off-diagonal path (wf1 only) ----
    {
        bf16x8 wf[4];
#pragma unroll
        for (int ks = 0; ks < 4; ++ks)
            wf[ks] = __builtin_bit_cast(bf16x8,
                *(const uint4*)(WT + (size_t)(F * F) + (size_t)grow * F + ks * 32 + lq * 8));
#pragma unroll
        for (int jj = 0; jj < JC; ++jj) {
            f32x4 h1 = {0.f, 0.f, 0.f, 0.f};
#pragma unroll
            for (int ks = 0; ks < 4; ++ks) {
                unsigned byte = (rbase + (unsigned)(jj * 256 + ks * 64 + lq * 16)) ^ swz;
                bf16x8 xf = __builtin_bit_cast(bf16x8, *(const uint4*)(xs + byte));
                h1 = __builtin_amdgcn_mfma_f32_16x16x32_bf16(wf[ks], xf, h1, 0, 0, 0);
            }
            const int j = J0 + jj;
            f32x4 mj  = *(const f32x4*)&Ms[j * F + gq];
            f32x4 mh1 = mj * h1;
#pragma unroll
            for (int i = 0; i < J; ++i)
                acc[i] = fma4(Aoff[i * J + j], mh1, acc[i]);
        }
    }
    __syncthreads();   // xs consumed; safe to restage / reuse
}

__global__ __launch_bounds__(THREADS, 2) void mgcn_kernel(
    const float* __restrict__ x, const float* __restrict__ Mw,
    const float* __restrict__ bias, const float* __restrict__ wsA,
    const unsigned short* __restrict__ WT, float* __restrict__ out) {

    __shared__ __align__(16) unsigned char xs[TB * JSTRIDE * F * 2];  // 36864 B
    __shared__ __align__(16) float Ms[J * F];                          //  8704 B

    const int tid = threadIdx.x;
    const int b0  = blockIdx.x * TB;

    for (int idx = tid; idx < J * F / 4; idx += THREADS)
        ((float4*)Ms)[idx] = ((const float4*)Mw)[idx];

    const int wave = tid >> 6;
    const int lane = tid & 63;
    const int lrow = lane & 15;           // MFMA 16-index: D col = batch
    const int lq   = lane >> 4;
    const int grow = wave * 16 + lrow;    // A-frag (W^T) row = g
    const int gq   = wave * 16 + lq * 4;  // D reg-quad g base

    const f32x4 bias4 = *(const f32x4*)(bias + gq);
    f32x4 acc[J];
#pragma unroll
    for (int i = 0; i < J; ++i) acc[i] = bias4;

    const float* __restrict__ Aoff  = wsA;
    const float* __restrict__ Adiag = wsA + J * J;

    chunk<9, 0>(x, xs, Ms, Aoff, Adiag, WT, acc, tid, b0, lrow, lq, grow, gq);
    chunk<8, 9>(x, xs, Ms, Aoff, Adiag, WT, acc, tid, b0, lrow, lq, grow, gq);

    // ---- epilogue: acc -> bf16 LDS tile (8 batches/round) -> coalesced f32 ----
#pragma unroll 1
    for (int r = 0; r < 2; ++r) {
        if (r) __syncthreads();            // round-0 readers done before re-write
        if ((lrow >> 3) == r) {
            const int bl = lrow & 7;
            const unsigned base = (unsigned)(bl * (J * 256) + gq * 2);
            const unsigned key  = (unsigned)((bl & 7) << 3);
#pragma unroll
            for (int i = 0; i < J; ++i) {
                ushort4 u;
                u.x = f2bf(acc[i][0]); u.y = f2bf(acc[i][1]);
                u.z = f2bf(acc[i][2]); u.w = f2bf(acc[i][3]);
                *(ushort4*)(xs + ((base + (unsigned)(i * 256)) ^ key)) = u;
            }
        }
        __syncthreads();
        const size_t gbase = ((size_t)b0 + r * 8) * (J * F);
        for (int idx = tid; idx < 8 * J * F / 4; idx += THREADS) {   // 4352
            unsigned byte = (unsigned)idx * 8u;
            unsigned bl   = byte / (unsigned)(J * 256);              // /4352
            ushort4 u = *(const ushort4*)(xs + (byte ^ ((bl & 7) << 3)));
            float4 o;
            o.x = bf2f(u.x); o.y = bf2f(u.y); o.z = bf2f(u.z); o.w = bf2f(u.w);
            *(float4*)(out + gbase + (size_t)idx * 4) = o;
        }
    }
}

extern "C" void kernel_launch(void* const* d_in, const int* in_sizes, int n_in,
                              void* d_out, int out_size, void* d_ws, size_t ws_size,
                              hipStream_t stream) {
    const float* x    = (const float*)d_in[0];
    const float* W    = (const float*)d_in[1];
    const float* Mw   = (const float*)d_in[2];
    const float* adj  = (const float*)d_in[3];
    const float* adj2 = (const float*)d_in[4];
    const float* bias = (const float*)d_in[5];
    float* out = (float*)d_out;
    float* wsA = (float*)d_ws;
    unsigned short* WT = (unsigned short*)((char*)d_ws + 2048);

    int Btot = in_sizes[0] / (J * F);   // 16384
    prep<<<16, 256, 0, stream>>>(W, adj, adj2, wsA, WT);
    mgcn_kernel<<<Btot / TB, THREADS, 0, stream>>>(x, Mw, bias, wsA, WT, out);
}